// Round 6
// baseline (92.821 us; speedup 1.0000x reference)
//
#include <hip/hip_runtime.h>
#include <hip/hip_bf16.h>

// Problem constants (fixed by the reference setup)
#define B_  16
#define C_  64
#define H_  64
#define W_  64
#define O_  64
#define EPS 1e-6f
#define SLOPE 0.01f

typedef __bf16  bf16x8 __attribute__((ext_vector_type(8)));
typedef float   f32x4  __attribute__((ext_vector_type(4)));

// ---- d_ws layout (bytes) ----
// Wt  @ 0        : bf16 [tap(9)][p(2)][o(64)][c2(32)]           = 73,728 B
// xt  @ 131072   : bf16 planes [b(16)][p(2)][q(4)][h*w(4096)][8] = 16,777,216 B
// pmm @ 16908288 : fp32 [map(2)][b(16)][p(2)][h*w(4096)]         = 1,048,576 B
#define XT_WS_OFF  131072
#define PMM_WS_OFF 16908288

__device__ __forceinline__ unsigned short f2bf(float f) {
  unsigned u = __float_as_uint(f);         // fp32 -> bf16 RNE
  u += 0x7fffu + ((u >> 16) & 1u);
  return (unsigned short)(u >> 16);
}

__device__ __forceinline__ int clampi(int v, int lo, int hi) {
  return v < lo ? lo : (v > hi ? hi : v);
}

// Transform W[o][c][j][i] (fp32) -> bf16 Wt[((tap*2+p)*64 + o)*32 + c2],
// tap = i*3+j (einsum 'bcijhw,ocji': tap (i,j) uses W[o][c][j][i]).
__global__ void wtransform_kernel(const float* __restrict__ Wsrc,
                                  unsigned short* __restrict__ Wt) {
  int idx = blockIdx.x * 256 + threadIdx.x;      // 64*64*9 = 36864 exact
  if (idx >= O_ * C_ * 9) return;
  int i = idx % 3;
  int j = (idx / 3) % 3;
  int c = (idx / 9) % C_;
  int o = idx / (9 * C_);
  int tap = i * 3 + j;
  Wt[((tap * 2 + (c & 1)) * 64 + o) * 32 + (c >> 1)] = f2bf(Wsrc[idx]);
}

// prep: block = (b, h); wave qq owns channels c in [qq*16, qq*16+16) for all
// 64 w. Coalesced 256 B reads; packs bf16 MFMA chunks into plane (b,p,qq);
// per-pixel channel min/max reduced across the 4 waves via 4 KB LDS.
__global__ __launch_bounds__(256)
void prep_kernel(const float* __restrict__ x,
                 char* __restrict__ xt,          // byte base of planes
                 float* __restrict__ pmm) {
  __shared__ float red[2][2][4][64];             // [map][p][qq][w]
  const int bb = blockIdx.x;
  const int b  = bb >> 6;
  const int h  = bb & 63;
  const int qq = threadIdx.x >> 6;
  const int w  = threadIdx.x & 63;

  const float* xp = x + (((size_t)b * C_ + qq * 16) * H_ + h) * W_ + w;
  float f[16];
  #pragma unroll
  for (int k = 0; k < 16; ++k) f[k] = xp[(size_t)k * (H_ * W_)];

  float mn[2] = {3.4e38f, 3.4e38f}, mx[2] = {-3.4e38f, -3.4e38f};
  unsigned pk[2][4];
  #pragma unroll
  for (int k = 0; k < 16; ++k) {
    const int p = k & 1, e = k >> 1;
    mn[p] = fminf(mn[p], f[k]);
    mx[p] = fmaxf(mx[p], f[k]);
    const unsigned h16 = f2bf(f[k]);
    if (e & 1) pk[p][e >> 1] |= (h16 << 16);
    else       pk[p][e >> 1]  = h16;
  }
  #pragma unroll
  for (int p = 0; p < 2; ++p)
    *(uint4*)(xt + ((size_t)(((b * 2 + p) * 4 + qq) * 4096) + h * 64 + w) * 16) =
        make_uint4(pk[p][0], pk[p][1], pk[p][2], pk[p][3]);

  red[0][0][qq][w] = mn[0];
  red[0][1][qq][w] = mn[1];
  red[1][0][qq][w] = mx[0];
  red[1][1][qq][w] = mx[1];
  __syncthreads();

  const int map = threadIdx.x >> 7;
  const int p   = (threadIdx.x >> 6) & 1;
  const int w2  = threadIdx.x & 63;
  float v;
  if (map == 0)
    v = fminf(fminf(red[0][p][0][w2], red[0][p][1][w2]),
              fminf(red[0][p][2][w2], red[0][p][3][w2]));
  else
    v = fmaxf(fmaxf(red[1][p][0][w2], red[1][p][1][w2]),
              fmaxf(red[1][p][2][w2], red[1][p][3][w2]));
  pmm[((size_t)(map * 16 + b) * 2 + p) * 4096 + h * 64 + w2] = v;
}

// gemm: no LDS, no barriers. Block = (b, h); wave wv owns o-slice o0 = wv*16
// for the full 64-w row. B-frags straight from global xt planes (coalesced,
// L1-shared across the block's 4 waves). s from pmm + separable shuffles.
__global__ __launch_bounds__(256, 4)
void gemm_kernel(const char* __restrict__ xt,
                 const unsigned short* __restrict__ Wt,
                 const float* __restrict__ pmm,
                 const float* __restrict__ bias,
                 float* __restrict__ out) {
  const int bb   = blockIdx.x;
  const int b    = bb >> 6;
  const int h    = bb & 63;
  const int wv   = threadIdx.x >> 6;
  const int lane = threadIdx.x & 63;
  const int l15  = lane & 15;
  const int q    = lane >> 4;
  const int o0   = wv * 16;

  // ---- per-lane (w = lane) scale factors: separable 3x3 window of pmm ----
  float si[2], se[2];
  #pragma unroll
  for (int p = 0; p < 2; ++p) {
    float mn = 3.4e38f, mx = -3.4e38f;
    #pragma unroll
    for (int r = 0; r < 3; ++r) {
      const int hr = clampi(h - 1 + r, 0, H_ - 1);
      mn = fminf(mn, pmm[((size_t)(0 * 16 + b) * 2 + p) * 4096 + hr * 64 + lane]);
      mx = fmaxf(mx, pmm[((size_t)(1 * 16 + b) * 2 + p) * 4096 + hr * 64 + lane]);
    }
    const float mnl = __shfl(mn, clampi(lane - 1, 0, 63));
    const float mnr = __shfl(mn, clampi(lane + 1, 0, 63));
    const float mxl = __shfl(mx, clampi(lane - 1, 0, 63));
    const float mxr = __shfl(mx, clampi(lane + 1, 0, 63));
    mn = fminf(mn, fminf(mnl, mnr));
    mx = fmaxf(mx, fmaxf(mxl, mxr));
    const float sv = (mx - mn) + EPS;
    se[p] = sv;
    si[p] = 1.0f / sv;
  }

  // ---- MFMA: one parity at a time; fold acc * 1/(s_p+eps) into oacc ----
  const f32x4 zero = {0.0f, 0.0f, 0.0f, 0.0f};
  f32x4 oacc[4];
  #pragma unroll
  for (int nt = 0; nt < 4; ++nt) oacc[nt] = zero;

  #pragma unroll 1
  for (int p = 0; p < 2; ++p) {
    bf16x8 af[9];                     // A[m=o][k=c2], m=l15, k=q*8+e
    #pragma unroll
    for (int t9 = 0; t9 < 9; ++t9)
      af[t9] = *(const bf16x8*)(Wt + ((t9 * 2 + p) * 64 + o0 + l15) * 32 + q * 8);

    const char* plane = xt + (size_t)(((b * 2 + p) * 4 + q) * 4096) * 16;
    f32x4 acc[4];
    #pragma unroll
    for (int nt = 0; nt < 4; ++nt) acc[nt] = zero;

    #pragma unroll
    for (int i = 0; i < 3; ++i) {
      const int hr = clampi(h - 1 + i, 0, H_ - 1);
      const char* row = plane + (size_t)hr * 64 * 16;
      #pragma unroll
      for (int nt = 0; nt < 4; ++nt) {
        bf16x8 bfr[3];                // B[k=c2][n=w], n=l15, k=q*8+e
        #pragma unroll
        for (int j = 0; j < 3; ++j) {
          const int wc = clampi(nt * 16 + l15 + j - 1, 0, W_ - 1);
          bfr[j] = *(const bf16x8*)(row + wc * 16);
        }
        #pragma unroll
        for (int j = 0; j < 3; ++j)
          acc[nt] = __builtin_amdgcn_mfma_f32_16x16x32_bf16(
              af[i * 3 + j], bfr[j], acc[nt], 0, 0, 0);
      }
    }

    #pragma unroll
    for (int nt = 0; nt < 4; ++nt) {
      const float sv = __shfl(si[p], nt * 16 + l15);
      #pragma unroll
      for (int reg = 0; reg < 4; ++reg)
        oacc[nt][reg] += acc[nt][reg] * sv;
    }
  }

  // ---- epilogue: bias, leaky-relu, re-scale by (s_{o%2}+eps), store ----
  // D layout: col(w) = l15, row(o-within-16) = q*4 + reg
  float bv[4];
  #pragma unroll
  for (int reg = 0; reg < 4; ++reg) bv[reg] = bias[o0 + q * 4 + reg];

  #pragma unroll
  for (int nt = 0; nt < 4; ++nt) {
    const int wpx = nt * 16 + l15;
    const float se0 = __shfl(se[0], wpx);
    const float se1 = __shfl(se[1], wpx);
    #pragma unroll
    for (int reg = 0; reg < 4; ++reg) {
      const int o = o0 + q * 4 + reg;
      float v = oacc[nt][reg] + bv[reg];
      v = v >= 0.0f ? v : SLOPE * v;
      v *= (reg & 1) ? se1 : se0;            // o&1 == reg&1 (q*4 even)
      out[(((size_t)b * O_ + o) * H_ + h) * W_ + wpx] = v;
    }
  }
}

extern "C" void kernel_launch(void* const* d_in, const int* in_sizes, int n_in,
                              void* d_out, int out_size, void* d_ws, size_t ws_size,
                              hipStream_t stream) {
  const float* x    = (const float*)d_in[0];
  const float* Wsrc = (const float*)d_in[1];
  const float* bias = (const float*)d_in[2];
  float* out = (float*)d_out;

  unsigned short* Wt = (unsigned short*)d_ws;
  char*  xt  = (char*)d_ws + XT_WS_OFF;
  float* pmm = (float*)((char*)d_ws + PMM_WS_OFF);

  wtransform_kernel<<<144, 256, 0, stream>>>(Wsrc, Wt);
  prep_kernel<<<1024, 256, 0, stream>>>(x, xt, pmm);
  gemm_kernel<<<1024, 256, 0, stream>>>(xt, Wt, pmm, bias, out);
}